// Round 1
// baseline (1239.036 us; speedup 1.0000x reference)
//
#include <hip/hip_runtime.h>
#include <hip/hip_bf16.h>

#define B_SZ 2
#define T_SEQ 2048
#define D_INN 4096
#define D_OUTT 4096
#define NH 32
#define NKV 8
#define DH 128
#define GRP 4

typedef unsigned short u16;
typedef __attribute__((ext_vector_type(8))) short short8;
typedef __attribute__((ext_vector_type(4))) float floatx4;

union U8 { u16 s[8]; uint4 v; };

__device__ inline u16 f2bf(float f) {
  __hip_bfloat16 h = __float2bfloat16(f);
  return *reinterpret_cast<u16*>(&h);
}
__device__ inline float bf2f(u16 u) {
  __hip_bfloat16 h;
  *reinterpret_cast<u16*>(&h) = u;
  return __bfloat162float(h);
}

__device__ inline void store_out(float* p, float v) { *p = v; }
__device__ inline void store_out(u16* p, float v) { *p = f2bf(v); }

// ---------------- cast x -> bf16 ----------------
__global__ void cast_x_kernel(const float* __restrict__ in, u16* __restrict__ out, int n8) {
  int idx = blockIdx.x * blockDim.x + threadIdx.x;
  if (idx >= n8) return;
  const float4* p = reinterpret_cast<const float4*>(in) + (size_t)idx * 2;
  float4 f0 = p[0], f1 = p[1];
  U8 u;
  u.s[0] = f2bf(f0.x); u.s[1] = f2bf(f0.y); u.s[2] = f2bf(f0.z); u.s[3] = f2bf(f0.w);
  u.s[4] = f2bf(f1.x); u.s[5] = f2bf(f1.y); u.s[6] = f2bf(f1.z); u.s[7] = f2bf(f1.w);
  *reinterpret_cast<uint4*>(out + (size_t)idx * 8) = u.v;
}

// ---------------- transpose + cast: W (K,N) f32 -> WT (N,K) bf16 ----------------
__global__ void transpose_cast_kernel(const float* __restrict__ W, u16* __restrict__ WT,
                                      int K, int N) {
  __shared__ u16 tile[64][72];
  int tid = threadIdx.x;
  int n0 = blockIdx.x * 64, k0 = blockIdx.y * 64;
  int r = tid >> 2, seg = (tid & 3) * 16;
  const float* wp = W + (size_t)(k0 + r) * N + n0 + seg;
#pragma unroll
  for (int jj = 0; jj < 4; ++jj) {
    float4 f = *(const float4*)(wp + jj * 4);
    tile[r][seg + jj * 4 + 0] = f2bf(f.x);
    tile[r][seg + jj * 4 + 1] = f2bf(f.y);
    tile[r][seg + jj * 4 + 2] = f2bf(f.z);
    tile[r][seg + jj * 4 + 3] = f2bf(f.w);
  }
  __syncthreads();
  u16* op = WT + (size_t)(n0 + r) * K + k0 + seg;
#pragma unroll
  for (int jj = 0; jj < 4; ++jj) {
    ushort4 o;
    o.x = tile[seg + jj * 4 + 0][r];
    o.y = tile[seg + jj * 4 + 1][r];
    o.z = tile[seg + jj * 4 + 2][r];
    o.w = tile[seg + jj * 4 + 3][r];
    *(ushort4*)(op + jj * 4) = o;
  }
}

// ---------------- RoPE in place, layout (B*T, H, DH) bf16 ----------------
__global__ void rope_kernel(u16* __restrict__ buf, int H, int total) {
  int idx = blockIdx.x * blockDim.x + threadIdx.x;
  if (idx >= total) return;
  int i = idx & 63;
  int head = (idx >> 6) % H;
  int bt = idx / (64 * H);
  int t = bt % T_SEQ;
  size_t base = ((size_t)bt * H + head) * DH;
  float x1 = bf2f(buf[base + i]);
  float x2 = bf2f(buf[base + 64 + i]);
  float expo = (float)i * (1.0f / 64.0f);
  float inv = powf(500000.0f, -expo);
  float ang = (float)t * inv;
  float c = cosf(ang), s = sinf(ang);
  buf[base + i]      = f2bf(x1 * c - x2 * s);
  buf[base + 64 + i] = f2bf(x1 * s + x2 * c);
}

// ---------------- GEMM: C[M,N] = A[M,K] * B[N,K]^T  (bf16 in, OutT out) ----------------
// 128x128 tile, BK=64, 256 threads = 4 waves in 2x2, each wave 64x64 (4x4 MFMA 16x16x32)
template <typename OutT>
__global__ __launch_bounds__(256) void gemm_bt(const u16* __restrict__ A,
                                               const u16* __restrict__ B,
                                               OutT* __restrict__ C,
                                               int M, int N, int Kd) {
  __shared__ u16 As[128][72];
  __shared__ u16 Bs[128][72];
  int tid = threadIdx.x;
  int wave = tid >> 6, lane = tid & 63;
  int l15 = lane & 15, quad = lane >> 4;
  int wr = wave >> 1, wc = wave & 1;
  int m0 = blockIdx.y * 128, n0 = blockIdx.x * 128;

  floatx4 acc[4][4];
#pragma unroll
  for (int mt = 0; mt < 4; ++mt)
#pragma unroll
    for (int nt = 0; nt < 4; ++nt)
#pragma unroll
      for (int r = 0; r < 4; ++r) acc[mt][nt][r] = 0.0f;

  int row = tid >> 1, seg = (tid & 1) * 32;
  const u16* ap = A + (size_t)(m0 + row) * Kd + seg;
  const u16* bp = B + (size_t)(n0 + row) * Kd + seg;

  for (int kt = 0; kt < Kd; kt += 64) {
    __syncthreads();
#pragma unroll
    for (int jj = 0; jj < 4; ++jj)
      *(uint4*)&As[row][seg + jj * 8] = *(const uint4*)(ap + kt + jj * 8);
#pragma unroll
    for (int jj = 0; jj < 4; ++jj)
      *(uint4*)&Bs[row][seg + jj * 8] = *(const uint4*)(bp + kt + jj * 8);
    __syncthreads();
#pragma unroll
    for (int ks = 0; ks < 2; ++ks) {
      short8 af[4], bfr[4];
#pragma unroll
      for (int mt = 0; mt < 4; ++mt)
        af[mt] = *(const short8*)&As[wr * 64 + mt * 16 + l15][ks * 32 + quad * 8];
#pragma unroll
      for (int nt = 0; nt < 4; ++nt)
        bfr[nt] = *(const short8*)&Bs[wc * 64 + nt * 16 + l15][ks * 32 + quad * 8];
#pragma unroll
      for (int mt = 0; mt < 4; ++mt)
#pragma unroll
        for (int nt = 0; nt < 4; ++nt)
          acc[mt][nt] = __builtin_amdgcn_mfma_f32_16x16x32_bf16(af[mt], bfr[nt], acc[mt][nt], 0, 0, 0);
    }
  }

#pragma unroll
  for (int mt = 0; mt < 4; ++mt)
#pragma unroll
    for (int nt = 0; nt < 4; ++nt)
#pragma unroll
      for (int r = 0; r < 4; ++r) {
        int rr = m0 + wr * 64 + mt * 16 + quad * 4 + r;
        int cc = n0 + wc * 64 + nt * 16 + l15;
        store_out(&C[(size_t)rr * N + cc], acc[mt][nt][r]);
      }
}

// ---------------- flash attention ----------------
// grid: (T/64, B*NH). block 256 = 4 waves; wave w owns q rows [q0+16w, q0+16w+16)
__global__ __launch_bounds__(256) void attn_kernel(const u16* __restrict__ Q,
                                                   const u16* __restrict__ K,
                                                   const u16* __restrict__ V,
                                                   u16* __restrict__ CTX) {
  const int bx = blockIdx.x;
  const int bh = blockIdx.y;
  const int b = bh >> 5, h = bh & 31;
  const int g = h >> 2;
  const int tid = threadIdx.x;
  const int wave = tid >> 6, lane = tid & 63;
  const int l15 = lane & 15, quad = lane >> 4;
  const int q0 = bx * 64;

  __shared__ u16 Ks[64][136];
  __shared__ u16 Vt[128][72];
  __shared__ u16 Ps[4][16][72];

  // Q fragments (A-operand layout), held across the K loop
  short8 aq[4];
  {
    int qrow = q0 + wave * 16 + l15;
    const u16* qptr = Q + ((size_t)(b * T_SEQ + qrow) * NH + h) * DH;
#pragma unroll
    for (int ks = 0; ks < 4; ++ks)
      aq[ks] = *(const short8*)(qptr + ks * 32 + quad * 8);
  }

  float m_r[4], ell_r[4];
  floatx4 o[8];
#pragma unroll
  for (int r = 0; r < 4; ++r) { m_r[r] = -1e30f; ell_r[r] = 0.0f; }
#pragma unroll
  for (int dt = 0; dt < 8; ++dt)
#pragma unroll
    for (int r = 0; r < 4; ++r) o[dt][r] = 0.0f;

  const float scale = 0.08838834764831845f;  // 1/sqrt(128)
  const int ntiles = bx + 1;

  for (int kt = 0; kt < ntiles; ++kt) {
    const int k0 = kt * 64;
    __syncthreads();
    {
      int row = tid >> 2, part = tid & 3;
      const u16* kp = K + ((size_t)(b * T_SEQ + k0 + row) * NKV + g) * DH + part * 32;
      const u16* vp = V + ((size_t)(b * T_SEQ + k0 + row) * NKV + g) * DH + part * 32;
#pragma unroll
      for (int jj = 0; jj < 4; ++jj)
        *(uint4*)&Ks[row][part * 32 + jj * 8] = *(const uint4*)(kp + jj * 8);
#pragma unroll
      for (int jj = 0; jj < 4; ++jj) {
        U8 u; u.v = *(const uint4*)(vp + jj * 8);
#pragma unroll
        for (int e = 0; e < 8; ++e)
          Vt[part * 32 + jj * 8 + e][row] = u.s[e];
      }
    }
    __syncthreads();

    // S = Q K^T  (16 q-rows x 64 keys per wave)
    floatx4 sacc[4];
#pragma unroll
    for (int nt = 0; nt < 4; ++nt)
#pragma unroll
      for (int r = 0; r < 4; ++r) sacc[nt][r] = 0.0f;
#pragma unroll
    for (int ks = 0; ks < 4; ++ks) {
#pragma unroll
      for (int nt = 0; nt < 4; ++nt) {
        short8 bk = *(const short8*)&Ks[nt * 16 + l15][ks * 32 + quad * 8];
        sacc[nt] = __builtin_amdgcn_mfma_f32_16x16x32_bf16(aq[ks], bk, sacc[nt], 0, 0, 0);
      }
    }

    float s[4][4];
#pragma unroll
    for (int nt = 0; nt < 4; ++nt)
#pragma unroll
      for (int r = 0; r < 4; ++r) s[nt][r] = sacc[nt][r] * scale;

    if (kt == bx) {  // diagonal tile: causal mask
#pragma unroll
      for (int nt = 0; nt < 4; ++nt) {
        int col = k0 + nt * 16 + l15;
#pragma unroll
        for (int r = 0; r < 4; ++r) {
          int rowg = q0 + wave * 16 + quad * 4 + r;
          if (col > rowg) s[nt][r] = -1e30f;
        }
      }
    }

    // row max across 4 nt + 16 lanes of the quad group
    float rmax[4];
#pragma unroll
    for (int r = 0; r < 4; ++r) {
      float m = s[0][r];
      m = fmaxf(m, s[1][r]); m = fmaxf(m, s[2][r]); m = fmaxf(m, s[3][r]);
      m = fmaxf(m, __shfl_xor(m, 1));
      m = fmaxf(m, __shfl_xor(m, 2));
      m = fmaxf(m, __shfl_xor(m, 4));
      m = fmaxf(m, __shfl_xor(m, 8));
      rmax[r] = m;
    }
    float alpha[4];
#pragma unroll
    for (int r = 0; r < 4; ++r) {
      float mnew = fmaxf(m_r[r], rmax[r]);
      alpha[r] = __expf(m_r[r] - mnew);
      m_r[r] = mnew;
    }
    // P = exp(s - m), rowsum
    float rsum[4];
#pragma unroll
    for (int r = 0; r < 4; ++r) {
      float acc_s = 0.0f;
#pragma unroll
      for (int nt = 0; nt < 4; ++nt) {
        float p = __expf(s[nt][r] - m_r[r]);
        s[nt][r] = p;
        acc_s += p;
      }
      acc_s += __shfl_xor(acc_s, 1);
      acc_s += __shfl_xor(acc_s, 2);
      acc_s += __shfl_xor(acc_s, 4);
      acc_s += __shfl_xor(acc_s, 8);
      rsum[r] = acc_s;
    }
#pragma unroll
    for (int r = 0; r < 4; ++r) ell_r[r] = ell_r[r] * alpha[r] + rsum[r];
#pragma unroll
    for (int dt = 0; dt < 8; ++dt)
#pragma unroll
      for (int r = 0; r < 4; ++r) o[dt][r] *= alpha[r];

    // P (C layout) -> LDS -> A layout
#pragma unroll
    for (int nt = 0; nt < 4; ++nt)
#pragma unroll
      for (int r = 0; r < 4; ++r)
        Ps[wave][quad * 4 + r][nt * 16 + l15] = f2bf(s[nt][r]);
    __syncthreads();

    short8 pf[2];
#pragma unroll
    for (int ks2 = 0; ks2 < 2; ++ks2)
      pf[ks2] = *(const short8*)&Ps[wave][l15][ks2 * 32 + quad * 8];

#pragma unroll
    for (int dt = 0; dt < 8; ++dt) {
#pragma unroll
      for (int ks2 = 0; ks2 < 2; ++ks2) {
        short8 bv = *(const short8*)&Vt[dt * 16 + l15][ks2 * 32 + quad * 8];
        o[dt] = __builtin_amdgcn_mfma_f32_16x16x32_bf16(pf[ks2], bv, o[dt], 0, 0, 0);
      }
    }
  }

  // epilogue: O / ell -> ctx (B,T,H,DH) bf16
  float inv_l[4];
#pragma unroll
  for (int r = 0; r < 4; ++r) inv_l[r] = 1.0f / ell_r[r];
#pragma unroll
  for (int dt = 0; dt < 8; ++dt)
#pragma unroll
    for (int r = 0; r < 4; ++r) {
      int rowg = q0 + wave * 16 + quad * 4 + r;
      CTX[((size_t)(b * T_SEQ + rowg) * NH + h) * DH + dt * 16 + l15] = f2bf(o[dt][r] * inv_l[r]);
    }
}

// ---------------- launcher ----------------
extern "C" void kernel_launch(void* const* d_in, const int* in_sizes, int n_in,
                              void* d_out, int out_size, void* d_ws, size_t ws_size,
                              hipStream_t stream) {
  const float* x  = (const float*)d_in[0];
  const float* Wq = (const float*)d_in[1];
  const float* Wk = (const float*)d_in[2];
  const float* Wv = (const float*)d_in[3];
  const float* Wo = (const float*)d_in[4];
  float* out = (float*)d_out;

  char* ws = (char*)d_ws;
  size_t off = 0;
  const size_t SZ_BIG = (size_t)4096 * 4096 * sizeof(u16);   // 33.5 MB
  const size_t SZ_KV  = (size_t)4096 * 1024 * sizeof(u16);   // 8.4 MB
  u16* xb  = (u16*)(ws + off); off += SZ_BIG;
  u16* wqT = (u16*)(ws + off); off += SZ_BIG;
  u16* wkT = (u16*)(ws + off); off += SZ_KV;
  u16* wvT = (u16*)(ws + off); off += SZ_KV;
  u16* woT = (u16*)(ws + off); off += SZ_BIG;
  u16* q   = (u16*)(ws + off); off += SZ_BIG;
  u16* k   = (u16*)(ws + off); off += SZ_KV;
  u16* v   = (u16*)(ws + off); off += SZ_KV;
  u16* ctx = (u16*)(ws + off); off += SZ_BIG;

  // cast x (16,777,216 elems, 8 per thread)
  cast_x_kernel<<<8192, 256, 0, stream>>>(x, xb, 2097152);
  // transpose+cast weights: W(K,N) -> WT(N,K)
  transpose_cast_kernel<<<dim3(64, 64), 256, 0, stream>>>(Wq, wqT, 4096, 4096);
  transpose_cast_kernel<<<dim3(16, 64), 256, 0, stream>>>(Wk, wkT, 4096, 1024);
  transpose_cast_kernel<<<dim3(16, 64), 256, 0, stream>>>(Wv, wvT, 4096, 1024);
  transpose_cast_kernel<<<dim3(64, 64), 256, 0, stream>>>(Wo, woT, 4096, 4096);

  // projections
  gemm_bt<u16><<<dim3(32, 32), 256, 0, stream>>>(xb, wqT, q, 4096, 4096, 4096);
  gemm_bt<u16><<<dim3(8, 32), 256, 0, stream>>>(xb, wkT, k, 4096, 1024, 4096);
  gemm_bt<u16><<<dim3(8, 32), 256, 0, stream>>>(xb, wvT, v, 4096, 1024, 4096);

  // RoPE in place
  rope_kernel<<<32768, 256, 0, stream>>>(q, NH, 8388608);
  rope_kernel<<<8192, 256, 0, stream>>>(k, NKV, 2097152);

  // attention
  attn_kernel<<<dim3(32, 64), 256, 0, stream>>>(q, k, v, ctx);

  // output projection (fp32 out)
  gemm_bt<float><<<dim3(32, 32), 256, 0, stream>>>(ctx, woT, out, 4096, 4096, 4096);
}

// Round 2
// 1043.092 us; speedup vs baseline: 1.1878x; 1.1878x over previous
//
#include <hip/hip_runtime.h>
#include <hip/hip_bf16.h>

#define T_SEQ 2048
#define NH 32
#define NKV 8
#define DH 128

typedef unsigned short u16;
typedef __attribute__((ext_vector_type(8))) short short8;
typedef __attribute__((ext_vector_type(4))) float floatx4;

union U8 { u16 s[8]; uint4 v; };

__device__ inline u16 f2bf(float f) {
  __hip_bfloat16 h = __float2bfloat16(f);
  return *reinterpret_cast<u16*>(&h);
}
__device__ inline float bf2f(u16 u) {
  __hip_bfloat16 h;
  *reinterpret_cast<u16*>(&h) = u;
  return __bfloat162float(h);
}

__device__ inline void store_out(float* p, float v) { *p = v; }
__device__ inline void store_out(u16* p, float v) { *p = f2bf(v); }

#define GLD_LDS(g, l) __builtin_amdgcn_global_load_lds( \
    (const __attribute__((address_space(1))) void*)(g), \
    (__attribute__((address_space(3))) void*)(l), 16, 0, 0)

// ---------------- cast x -> bf16 ----------------
__global__ void cast_x_kernel(const float* __restrict__ in, u16* __restrict__ out, int n8) {
  int idx = blockIdx.x * blockDim.x + threadIdx.x;
  if (idx >= n8) return;
  const float4* p = reinterpret_cast<const float4*>(in) + (size_t)idx * 2;
  float4 f0 = p[0], f1 = p[1];
  U8 u;
  u.s[0] = f2bf(f0.x); u.s[1] = f2bf(f0.y); u.s[2] = f2bf(f0.z); u.s[3] = f2bf(f0.w);
  u.s[4] = f2bf(f1.x); u.s[5] = f2bf(f1.y); u.s[6] = f2bf(f1.z); u.s[7] = f2bf(f1.w);
  *reinterpret_cast<uint4*>(out + (size_t)idx * 8) = u.v;
}

// ---------------- transpose + cast: W (K,N) f32 -> WT (N,K) bf16 ----------------
__global__ void transpose_cast_kernel(const float* __restrict__ W, u16* __restrict__ WT,
                                      int K, int N) {
  __shared__ u16 tile[64][72];
  int tid = threadIdx.x;
  int n0 = blockIdx.x * 64, k0 = blockIdx.y * 64;
  int r = tid >> 2, seg = (tid & 3) * 16;
  const float* wp = W + (size_t)(k0 + r) * N + n0 + seg;
#pragma unroll
  for (int jj = 0; jj < 4; ++jj) {
    float4 f = *(const float4*)(wp + jj * 4);
    tile[r][seg + jj * 4 + 0] = f2bf(f.x);
    tile[r][seg + jj * 4 + 1] = f2bf(f.y);
    tile[r][seg + jj * 4 + 2] = f2bf(f.z);
    tile[r][seg + jj * 4 + 3] = f2bf(f.w);
  }
  __syncthreads();
  u16* op = WT + (size_t)(n0 + r) * K + k0 + seg;
#pragma unroll
  for (int jj = 0; jj < 4; ++jj) {
    ushort4 o;
    o.x = tile[seg + jj * 4 + 0][r];
    o.y = tile[seg + jj * 4 + 1][r];
    o.z = tile[seg + jj * 4 + 2][r];
    o.w = tile[seg + jj * 4 + 3][r];
    *(ushort4*)(op + jj * 4) = o;
  }
}

// ---------------- RoPE in place on qkv rows (stride 6144) ----------------
// heads 0..31 = q at col h*128; heads 32..39 = k at col 4096+(h-32)*128
__global__ void rope_kernel(u16* __restrict__ qkv) {
  int idx = blockIdx.x * blockDim.x + threadIdx.x;  // 4096*40*64 threads
  int i = idx & 63;
  int head = (idx >> 6) % 40;
  int row = idx / (64 * 40);
  int t = row & (T_SEQ - 1);
  int col = head < 32 ? head * 128 : 4096 + (head - 32) * 128;
  size_t base = (size_t)row * 6144 + col;
  float x1 = bf2f(qkv[base + i]);
  float x2 = bf2f(qkv[base + 64 + i]);
  // inv_freq = 500000^(-i/64) = exp2(-i * log2(500000)/64)
  float inv = exp2f(-(float)i * (18.931568569324174f / 64.0f));
  float ang = (float)t * inv;
  float c = cosf(ang), s = sinf(ang);
  qkv[base + i]      = f2bf(x1 * c - x2 * s);
  qkv[base + 64 + i] = f2bf(x1 * s + x2 * c);
}

// ---------------- V transpose: qkv[row][5120+g*128+d] -> vt[(bg*128+d)*2048 + t] ----------------
__global__ void vtrans_kernel(const u16* __restrict__ qkv, u16* __restrict__ vt) {
  __shared__ u16 tile[64][72];
  int tid = threadIdx.x;
  int t0 = blockIdx.x * 64, d0 = blockIdx.y * 64, bg = blockIdx.z;
  int b = bg >> 3, g = bg & 7;
  int r = tid >> 2, seg = (tid & 3) * 16;
  const u16* src = qkv + (size_t)(b * T_SEQ + t0 + r) * 6144 + 5120 + g * 128 + d0 + seg;
  *(uint4*)&tile[r][seg] = *(const uint4*)src;
  *(uint4*)&tile[r][seg + 8] = *(const uint4*)(src + 8);
  __syncthreads();
  u16* dst = vt + (size_t)(bg * 128 + d0 + r) * T_SEQ + t0 + seg;
  U8 o0, o1;
#pragma unroll
  for (int e = 0; e < 8; ++e) o0.s[e] = tile[seg + e][r];
#pragma unroll
  for (int e = 0; e < 8; ++e) o1.s[e] = tile[seg + 8 + e][r];
  *(uint4*)dst = o0.v;
  *(uint4*)(dst + 8) = o1.v;
}

// ---------------- GEMM: C[M,N] = A[M,K] * B[N,K]^T  (bf16 in, OutT out) ----------------
// m97-class: 128x128 tile, BK=64, global_load_lds(16B) staging, XOR-swizzled LDS.
template <typename OutT>
__global__ __launch_bounds__(256) void gemm_bt(const u16* __restrict__ A,
                                               const u16* __restrict__ B,
                                               OutT* __restrict__ C,
                                               int M, int N, int Kd, int ldc) {
  __shared__ u16 As[128 * 64];
  __shared__ u16 Bs[128 * 64];
  int tid = threadIdx.x;
  int wave = tid >> 6, lane = tid & 63;
  int l15 = lane & 15, quad = lane >> 4;
  int wr = wave >> 1, wc = wave & 1;
  int m0 = blockIdx.y * 128, n0 = blockIdx.x * 128;

  floatx4 acc[4][4];
#pragma unroll
  for (int mt = 0; mt < 4; ++mt)
#pragma unroll
    for (int nt = 0; nt < 4; ++nt)
#pragma unroll
      for (int r = 0; r < 4; ++r) acc[mt][nt][r] = 0.0f;

  // staging: lane i handles row (i>>3), slot (i&7); global chunk = slot ^ (row&7)
  int rloc = lane >> 3, slot = lane & 7;
  const u16* agp = A + (size_t)(m0 + wave * 32 + rloc) * Kd + ((slot ^ rloc) * 8);
  const u16* bgp = B + (size_t)(n0 + wave * 32 + rloc) * Kd + ((slot ^ rloc) * 8);
  u16* alp = As + (wave * 32) * 64;
  u16* blp = Bs + (wave * 32) * 64;

  for (int kt = 0; kt < Kd; kt += 64) {
    __syncthreads();
#pragma unroll
    for (int j = 0; j < 4; ++j) {
      GLD_LDS(agp + kt + (size_t)j * 8 * Kd, alp + j * 8 * 64);
      GLD_LDS(bgp + kt + (size_t)j * 8 * Kd, blp + j * 8 * 64);
    }
    __syncthreads();
#pragma unroll
    for (int ks = 0; ks < 2; ++ks) {
      short8 af[4], bfr[4];
      int sl = ((ks * 4 + quad) ^ (l15 & 7)) * 8;
#pragma unroll
      for (int mt = 0; mt < 4; ++mt)
        af[mt] = *(const short8*)&As[(wr * 64 + mt * 16 + l15) * 64 + sl];
#pragma unroll
      for (int nt = 0; nt < 4; ++nt)
        bfr[nt] = *(const short8*)&Bs[(wc * 64 + nt * 16 + l15) * 64 + sl];
#pragma unroll
      for (int mt = 0; mt < 4; ++mt)
#pragma unroll
        for (int nt = 0; nt < 4; ++nt)
          acc[mt][nt] = __builtin_amdgcn_mfma_f32_16x16x32_bf16(af[mt], bfr[nt], acc[mt][nt], 0, 0, 0);
    }
  }

#pragma unroll
  for (int mt = 0; mt < 4; ++mt)
#pragma unroll
    for (int nt = 0; nt < 4; ++nt)
#pragma unroll
      for (int r = 0; r < 4; ++r) {
        int rr = m0 + wr * 64 + mt * 16 + quad * 4 + r;
        int cc = n0 + wc * 64 + nt * 16 + l15;
        store_out(&C[(size_t)rr * ldc + cc], acc[mt][nt][r]);
      }
}

// ---------------- flash attention ----------------
// grid (16, B*NH). block 256 = 4 waves. Q-tile 128 (32 rows/wave), K-tile 64.
// K and V^T staged via global_load_lds with XOR swizzle; Ps is wave-private (no barrier).
__global__ __launch_bounds__(256) void attn_kernel(const u16* __restrict__ qkv,
                                                   const u16* __restrict__ vt,
                                                   u16* __restrict__ CTX) {
  const int bx = (gridDim.x - 1) - blockIdx.x;  // heavy blocks first
  const int bh = blockIdx.y;
  const int b = bh >> 5, h = bh & 31;
  const int g = h >> 2;
  const int bg = b * NKV + g;
  const int tid = threadIdx.x;
  const int w = tid >> 6, lane = tid & 63;
  const int l15 = lane & 15, quad = lane >> 4;
  const int q0 = bx * 128;

  __shared__ u16 Ks[64 * 128];
  __shared__ u16 Vs[128 * 64];
  __shared__ u16 Ps[4][32 * 72];

  // Q fragments (A-operand), held across the K loop
  short8 aq[2][4];
#pragma unroll
  for (int mf = 0; mf < 2; ++mf) {
    int qrow = q0 + w * 32 + mf * 16 + l15;
    const u16* qp = qkv + (size_t)(b * T_SEQ + qrow) * 6144 + h * 128;
#pragma unroll
    for (int ks = 0; ks < 4; ++ks)
      aq[mf][ks] = *(const short8*)(qp + ks * 32 + quad * 8);
  }

  float m_r[2][4], ell[2][4];
  floatx4 o[2][8];
#pragma unroll
  for (int mf = 0; mf < 2; ++mf)
#pragma unroll
    for (int r = 0; r < 4; ++r) { m_r[mf][r] = -1e30f; ell[mf][r] = 0.0f; }
#pragma unroll
  for (int mf = 0; mf < 2; ++mf)
#pragma unroll
    for (int dt = 0; dt < 8; ++dt)
#pragma unroll
      for (int r = 0; r < 4; ++r) o[mf][dt][r] = 0.0f;

  const float scale = 0.08838834764831845f;  // 1/sqrt(128)
  const int ntiles = 2 * bx + 2;

  const int krloc = lane >> 4, kslot = lane & 15;  // K staging: 4 rows / wave-load
  const int vrloc = lane >> 3, vslot = lane & 7;   // V staging: 8 rows / wave-load
  const u16* kbase = qkv + (size_t)(b * T_SEQ) * 6144 + 4096 + g * 128;
  const u16* vbase = vt + (size_t)(bg * 128) * T_SEQ;

  for (int kt = 0; kt < ntiles; ++kt) {
    const int k0 = kt * 64;
    __syncthreads();
#pragma unroll
    for (int j = 0; j < 4; ++j) {
      int rk = w * 16 + j * 4 + krloc;
      int gck = (kslot & 8) | ((kslot & 7) ^ (rk & 7));
      GLD_LDS(kbase + (size_t)(k0 + rk) * 6144 + gck * 8, Ks + (w * 16 + j * 4) * 128);
      int rv = w * 32 + j * 8 + vrloc;  // rv&7 == vrloc
      int gcv = vslot ^ vrloc;
      GLD_LDS(vbase + (size_t)rv * T_SEQ + k0 + gcv * 8, Vs + (w * 32 + j * 8) * 64);
    }
    __syncthreads();

    if (k0 > q0 + w * 32 + 31) continue;  // wave-uniform: this wave's rows all < k0

    // S = Q K^T : per wave 32 q-rows x 64 keys
    floatx4 sacc[2][4];
#pragma unroll
    for (int mf = 0; mf < 2; ++mf)
#pragma unroll
      for (int nt = 0; nt < 4; ++nt)
#pragma unroll
        for (int r = 0; r < 4; ++r) sacc[mf][nt][r] = 0.0f;
#pragma unroll
    for (int ks = 0; ks < 4; ++ks) {
      int c = ks * 4 + quad;
      int sl = ((c & 8) | ((c & 7) ^ (l15 & 7))) * 8;
#pragma unroll
      for (int nt = 0; nt < 4; ++nt) {
        short8 bk = *(const short8*)&Ks[(nt * 16 + l15) * 128 + sl];
        sacc[0][nt] = __builtin_amdgcn_mfma_f32_16x16x32_bf16(aq[0][ks], bk, sacc[0][nt], 0, 0, 0);
        sacc[1][nt] = __builtin_amdgcn_mfma_f32_16x16x32_bf16(aq[1][ks], bk, sacc[1][nt], 0, 0, 0);
      }
    }

#pragma unroll
    for (int mf = 0; mf < 2; ++mf) {
      const int rowbase = q0 + w * 32 + mf * 16;
      float s[4][4];
#pragma unroll
      for (int nt = 0; nt < 4; ++nt)
#pragma unroll
        for (int r = 0; r < 4; ++r) s[nt][r] = sacc[mf][nt][r] * scale;

      if (k0 + 63 > rowbase) {  // tile not fully below diagonal for this frag
#pragma unroll
        for (int nt = 0; nt < 4; ++nt) {
          int col = k0 + nt * 16 + l15;
#pragma unroll
          for (int r = 0; r < 4; ++r) {
            int row = rowbase + quad * 4 + r;
            if (col > row) s[nt][r] = -1e30f;
          }
        }
      }

      float alpha[4];
#pragma unroll
      for (int r = 0; r < 4; ++r) {
        float m = fmaxf(fmaxf(s[0][r], s[1][r]), fmaxf(s[2][r], s[3][r]));
        m = fmaxf(m, __shfl_xor(m, 1));
        m = fmaxf(m, __shfl_xor(m, 2));
        m = fmaxf(m, __shfl_xor(m, 4));
        m = fmaxf(m, __shfl_xor(m, 8));
        float mnew = fmaxf(m_r[mf][r], m);
        alpha[r] = __expf(m_r[mf][r] - mnew);
        m_r[mf][r] = mnew;
      }
      float rsum[4];
#pragma unroll
      for (int r = 0; r < 4; ++r) {
        float acc_s = 0.0f;
#pragma unroll
        for (int nt = 0; nt < 4; ++nt) {
          float p = __expf(s[nt][r] - m_r[mf][r]);
          s[nt][r] = p;
          acc_s += p;
        }
        acc_s += __shfl_xor(acc_s, 1);
        acc_s += __shfl_xor(acc_s, 2);
        acc_s += __shfl_xor(acc_s, 4);
        acc_s += __shfl_xor(acc_s, 8);
        rsum[r] = acc_s;
      }
#pragma unroll
      for (int r = 0; r < 4; ++r) ell[mf][r] = ell[mf][r] * alpha[r] + rsum[r];
#pragma unroll
      for (int dt = 0; dt < 8; ++dt)
#pragma unroll
        for (int r = 0; r < 4; ++r) o[mf][dt][r] *= alpha[r];

      // P (C-layout) -> wave-private LDS (no barrier needed)
#pragma unroll
      for (int nt = 0; nt < 4; ++nt)
#pragma unroll
        for (int r = 0; r < 4; ++r)
          Ps[w][(mf * 16 + quad * 4 + r) * 72 + nt * 16 + l15] = f2bf(s[nt][r]);
    }

    // P fragments (A-operand layout)
    short8 pf[2][2];
#pragma unroll
    for (int mf = 0; mf < 2; ++mf)
#pragma unroll
      for (int ks2 = 0; ks2 < 2; ++ks2)
        pf[mf][ks2] = *(const short8*)&Ps[w][(mf * 16 + l15) * 72 + ks2 * 32 + quad * 8];

    // O += P V
#pragma unroll
    for (int dt = 0; dt < 8; ++dt) {
#pragma unroll
      for (int ks2 = 0; ks2 < 2; ++ks2) {
        int sl = (((ks2 * 4 + quad) ^ (l15 & 7))) * 8;
        short8 bv = *(const short8*)&Vs[(dt * 16 + l15) * 64 + sl];
        o[0][dt] = __builtin_amdgcn_mfma_f32_16x16x32_bf16(pf[0][ks2], bv, o[0][dt], 0, 0, 0);
        o[1][dt] = __builtin_amdgcn_mfma_f32_16x16x32_bf16(pf[1][ks2], bv, o[1][dt], 0, 0, 0);
      }
    }
  }

  // epilogue
#pragma unroll
  for (int mf = 0; mf < 2; ++mf) {
    float inv_l[4];
#pragma unroll
    for (int r = 0; r < 4; ++r) inv_l[r] = 1.0f / ell[mf][r];
#pragma unroll
    for (int dt = 0; dt < 8; ++dt)
#pragma unroll
      for (int r = 0; r < 4; ++r) {
        int row = q0 + w * 32 + mf * 16 + quad * 4 + r;
        CTX[(size_t)(b * T_SEQ + row) * 4096 + h * 128 + dt * 16 + l15] =
            f2bf(o[mf][dt][r] * inv_l[r]);
      }
  }
}

// ---------------- launcher ----------------
extern "C" void kernel_launch(void* const* d_in, const int* in_sizes, int n_in,
                              void* d_out, int out_size, void* d_ws, size_t ws_size,
                              hipStream_t stream) {
  const float* x  = (const float*)d_in[0];
  const float* Wq = (const float*)d_in[1];
  const float* Wk = (const float*)d_in[2];
  const float* Wv = (const float*)d_in[3];
  const float* Wo = (const float*)d_in[4];
  float* out = (float*)d_out;

  char* ws = (char*)d_ws;
  const size_t SZ_X    = (size_t)4096 * 4096 * 2;  // 33.5 MB
  const size_t SZ_QKVW = (size_t)6144 * 4096 * 2;  // 50.3 MB
  u16* xb    = (u16*)(ws);                          // also ctx (aliased; x dead after QKV GEMM)
  u16* wqkvT = (u16*)(ws + SZ_X);
  u16* woT   = (u16*)(ws + SZ_X + SZ_QKVW);
  u16* qkv   = (u16*)(ws + SZ_X + SZ_QKVW + SZ_X);
  u16* vt    = (u16*)(ws + SZ_X + SZ_QKVW + SZ_X + SZ_QKVW);
  u16* ctx   = xb;

  // cast x (16.7M elems, 8/thread)
  cast_x_kernel<<<8192, 256, 0, stream>>>(x, xb, 2097152);
  // weights: W(K,N) -> WT(N,K), QKV packed row-contiguous [Wq; Wk; Wv]
  transpose_cast_kernel<<<dim3(64, 64), 256, 0, stream>>>(Wq, wqkvT, 4096, 4096);
  transpose_cast_kernel<<<dim3(16, 64), 256, 0, stream>>>(Wk, wqkvT + (size_t)4096 * 4096, 4096, 1024);
  transpose_cast_kernel<<<dim3(16, 64), 256, 0, stream>>>(Wv, wqkvT + (size_t)5120 * 4096, 4096, 1024);
  transpose_cast_kernel<<<dim3(64, 64), 256, 0, stream>>>(Wo, woT, 4096, 4096);

  // fused QKV projection: (4096 x 4096) @ (4096 x 6144) -> qkv
  gemm_bt<u16><<<dim3(48, 32), 256, 0, stream>>>(xb, wqkvT, qkv, 4096, 6144, 4096, 6144);

  // RoPE on q + k columns of qkv (4096 rows * 40 heads * 64 lanes)
  rope_kernel<<<40960, 256, 0, stream>>>(qkv);

  // V -> V^T (per b,g: DH x T)
  vtrans_kernel<<<dim3(32, 2, 16), 256, 0, stream>>>(qkv, vt);

  // attention
  attn_kernel<<<dim3(16, 64), 256, 0, stream>>>(qkv, vt, ctx);

  // output projection (fp32 out)
  gemm_bt<float><<<dim3(32, 32), 256, 0, stream>>>(ctx, woT, out, 4096, 4096, 4096, 4096);
}

// Round 3
// 919.571 us; speedup vs baseline: 1.3474x; 1.1343x over previous
//
#include <hip/hip_runtime.h>
#include <hip/hip_bf16.h>

#define T_SEQ 2048
#define NH 32
#define NKV 8
#define DH 128

typedef unsigned short u16;
typedef unsigned int u32;
typedef __attribute__((ext_vector_type(8))) short short8;
typedef __attribute__((ext_vector_type(4))) float floatx4;

union U8 { u16 s[8]; uint4 v; };
union F8 { u32 d[4]; short8 s; };

__device__ inline u16 f2bf(float f) {
  __hip_bfloat16 h = __float2bfloat16(f);
  return *reinterpret_cast<u16*>(&h);
}
__device__ inline float bf2f(u16 u) {
  __hip_bfloat16 h;
  *reinterpret_cast<u16*>(&h) = u;
  return __bfloat162float(h);
}

__device__ inline void store_out(float* p, float v) { *p = v; }
__device__ inline void store_out(u16* p, float v) { *p = f2bf(v); }

#define GLD_LDS(g, l) __builtin_amdgcn_global_load_lds( \
    (const __attribute__((address_space(1))) void*)(g), \
    (__attribute__((address_space(3))) void*)(l), 16, 0, 0)

// ---------------- cast x -> bf16 ----------------
__global__ void cast_x_kernel(const float* __restrict__ in, u16* __restrict__ out, int n8) {
  int idx = blockIdx.x * blockDim.x + threadIdx.x;
  if (idx >= n8) return;
  const float4* p = reinterpret_cast<const float4*>(in) + (size_t)idx * 2;
  float4 f0 = p[0], f1 = p[1];
  U8 u;
  u.s[0] = f2bf(f0.x); u.s[1] = f2bf(f0.y); u.s[2] = f2bf(f0.z); u.s[3] = f2bf(f0.w);
  u.s[4] = f2bf(f1.x); u.s[5] = f2bf(f1.y); u.s[6] = f2bf(f1.z); u.s[7] = f2bf(f1.w);
  *reinterpret_cast<uint4*>(out + (size_t)idx * 8) = u.v;
}

// ---------------- transpose + cast: W (K,N) f32 -> WT (N,K) bf16 ----------------
__global__ void transpose_cast_kernel(const float* __restrict__ W, u16* __restrict__ WT,
                                      int K, int N) {
  __shared__ u16 tile[64][72];
  int tid = threadIdx.x;
  int n0 = blockIdx.x * 64, k0 = blockIdx.y * 64;
  int r = tid >> 2, seg = (tid & 3) * 16;
  const float* wp = W + (size_t)(k0 + r) * N + n0 + seg;
#pragma unroll
  for (int jj = 0; jj < 4; ++jj) {
    float4 f = *(const float4*)(wp + jj * 4);
    tile[r][seg + jj * 4 + 0] = f2bf(f.x);
    tile[r][seg + jj * 4 + 1] = f2bf(f.y);
    tile[r][seg + jj * 4 + 2] = f2bf(f.z);
    tile[r][seg + jj * 4 + 3] = f2bf(f.w);
  }
  __syncthreads();
  u16* op = WT + (size_t)(n0 + r) * K + k0 + seg;
#pragma unroll
  for (int jj = 0; jj < 4; ++jj) {
    ushort4 o;
    o.x = tile[seg + jj * 4 + 0][r];
    o.y = tile[seg + jj * 4 + 1][r];
    o.z = tile[seg + jj * 4 + 2][r];
    o.w = tile[seg + jj * 4 + 3][r];
    *(ushort4*)(op + jj * 4) = o;
  }
}

// ---------------- RoPE in place on qkv rows (stride 6144) ----------------
__global__ void rope_kernel(u16* __restrict__ qkv) {
  int idx = blockIdx.x * blockDim.x + threadIdx.x;
  int i = idx & 63;
  int head = (idx >> 6) % 40;
  int row = idx / (64 * 40);
  int t = row & (T_SEQ - 1);
  int col = head < 32 ? head * 128 : 4096 + (head - 32) * 128;
  size_t base = (size_t)row * 6144 + col;
  float x1 = bf2f(qkv[base + i]);
  float x2 = bf2f(qkv[base + 64 + i]);
  float inv = exp2f(-(float)i * (18.931568569324174f / 64.0f));
  float ang = (float)t * inv;
  float c = cosf(ang), s = sinf(ang);
  qkv[base + i]      = f2bf(x1 * c - x2 * s);
  qkv[base + 64 + i] = f2bf(x1 * s + x2 * c);
}

// ---------------- V transpose ----------------
__global__ void vtrans_kernel(const u16* __restrict__ qkv, u16* __restrict__ vt) {
  __shared__ u16 tile[64][72];
  int tid = threadIdx.x;
  int t0 = blockIdx.x * 64, d0 = blockIdx.y * 64, bg = blockIdx.z;
  int b = bg >> 3, g = bg & 7;
  int r = tid >> 2, seg = (tid & 3) * 16;
  const u16* src = qkv + (size_t)(b * T_SEQ + t0 + r) * 6144 + 5120 + g * 128 + d0 + seg;
  *(uint4*)&tile[r][seg] = *(const uint4*)src;
  *(uint4*)&tile[r][seg + 8] = *(const uint4*)(src + 8);
  __syncthreads();
  u16* dst = vt + (size_t)(bg * 128 + d0 + r) * T_SEQ + t0 + seg;
  U8 o0, o1;
#pragma unroll
  for (int e = 0; e < 8; ++e) o0.s[e] = tile[seg + e][r];
#pragma unroll
  for (int e = 0; e < 8; ++e) o1.s[e] = tile[seg + 8 + e][r];
  *(uint4*)dst = o0.v;
  *(uint4*)(dst + 8) = o1.v;
}

// ---------------- GEMM (m97-class, unchanged) ----------------
template <typename OutT>
__global__ __launch_bounds__(256) void gemm_bt(const u16* __restrict__ A,
                                               const u16* __restrict__ B,
                                               OutT* __restrict__ C,
                                               int M, int N, int Kd, int ldc) {
  __shared__ u16 As[128 * 64];
  __shared__ u16 Bs[128 * 64];
  int tid = threadIdx.x;
  int wave = tid >> 6, lane = tid & 63;
  int l15 = lane & 15, quad = lane >> 4;
  int wr = wave >> 1, wc = wave & 1;
  int m0 = blockIdx.y * 128, n0 = blockIdx.x * 128;

  floatx4 acc[4][4];
#pragma unroll
  for (int mt = 0; mt < 4; ++mt)
#pragma unroll
    for (int nt = 0; nt < 4; ++nt)
#pragma unroll
      for (int r = 0; r < 4; ++r) acc[mt][nt][r] = 0.0f;

  int rloc = lane >> 3, slot = lane & 7;
  const u16* agp = A + (size_t)(m0 + wave * 32 + rloc) * Kd + ((slot ^ rloc) * 8);
  const u16* bgp = B + (size_t)(n0 + wave * 32 + rloc) * Kd + ((slot ^ rloc) * 8);
  u16* alp = As + (wave * 32) * 64;
  u16* blp = Bs + (wave * 32) * 64;

  for (int kt = 0; kt < Kd; kt += 64) {
    __syncthreads();
#pragma unroll
    for (int j = 0; j < 4; ++j) {
      GLD_LDS(agp + kt + (size_t)j * 8 * Kd, alp + j * 8 * 64);
      GLD_LDS(bgp + kt + (size_t)j * 8 * Kd, blp + j * 8 * 64);
    }
    __syncthreads();
#pragma unroll
    for (int ks = 0; ks < 2; ++ks) {
      short8 af[4], bfr[4];
      int sl = ((ks * 4 + quad) ^ (l15 & 7)) * 8;
#pragma unroll
      for (int mt = 0; mt < 4; ++mt)
        af[mt] = *(const short8*)&As[(wr * 64 + mt * 16 + l15) * 64 + sl];
#pragma unroll
      for (int nt = 0; nt < 4; ++nt)
        bfr[nt] = *(const short8*)&Bs[(wc * 64 + nt * 16 + l15) * 64 + sl];
#pragma unroll
      for (int mt = 0; mt < 4; ++mt)
#pragma unroll
        for (int nt = 0; nt < 4; ++nt)
          acc[mt][nt] = __builtin_amdgcn_mfma_f32_16x16x32_bf16(af[mt], bfr[nt], acc[mt][nt], 0, 0, 0);
    }
  }

#pragma unroll
  for (int mt = 0; mt < 4; ++mt)
#pragma unroll
    for (int nt = 0; nt < 4; ++nt)
#pragma unroll
      for (int r = 0; r < 4; ++r) {
        int rr = m0 + wr * 64 + mt * 16 + quad * 4 + r;
        int cc = n0 + wc * 64 + nt * 16 + l15;
        store_out(&C[(size_t)rr * ldc + cc], acc[mt][nt][r]);
      }
}

// ---------------- flash attention v3 ----------------
// grid (16, 64). Block bx owns paired 64-row q-tiles {lo=bx, hi=31-bx}; K-tile 64.
// S^T formulation (lane owns one q-column), shfl-assembled P^T, 1-barrier dbuf staging.
__device__ inline void softmax_pv(floatx4* sc, float& m_s, float& ell_s,
                                  floatx4* o, const u16* Vsb,
                                  int qglob, int k0, bool diag,
                                  int l15, int quad) {
  const float scale = 0.08838834764831845f;  // 1/sqrt(128)
  float s[4][4];
#pragma unroll
  for (int t4 = 0; t4 < 4; ++t4)
#pragma unroll
    for (int r = 0; r < 4; ++r) {
      float v = sc[t4][r] * scale;
      if (diag && (k0 + t4 * 16 + quad * 4 + r > qglob)) v = -1e30f;
      s[t4][r] = v;
    }
  float m = s[0][0];
#pragma unroll
  for (int t4 = 0; t4 < 4; ++t4)
#pragma unroll
    for (int r = 0; r < 4; ++r) m = fmaxf(m, s[t4][r]);
  m = fmaxf(m, __shfl_xor(m, 16));
  m = fmaxf(m, __shfl_xor(m, 32));
  float mnew = fmaxf(m_s, m);
  float alpha = __expf(m_s - mnew);
  m_s = mnew;
  float sum = 0.f;
#pragma unroll
  for (int t4 = 0; t4 < 4; ++t4)
#pragma unroll
    for (int r = 0; r < 4; ++r) {
      float p = __expf(s[t4][r] - mnew);
      s[t4][r] = p;
      sum += p;
    }
  sum += __shfl_xor(sum, 16);
  sum += __shfl_xor(sum, 32);
  ell_s = ell_s * alpha + sum;
#pragma unroll
  for (int dt = 0; dt < 8; ++dt)
#pragma unroll
    for (int r = 0; r < 4; ++r) o[dt][r] *= alpha;

  // pack P^T rows into bf16x2 dwords: pk[t4][i] = (p[2i], p[2i+1])
  u32 pk[4][2];
#pragma unroll
  for (int t4 = 0; t4 < 4; ++t4) {
    pk[t4][0] = (u32)f2bf(s[t4][0]) | ((u32)f2bf(s[t4][1]) << 16);
    pk[t4][1] = (u32)f2bf(s[t4][2]) | ((u32)f2bf(s[t4][3]) << 16);
  }
  // assemble B-operand frags: frag[h] elem j = P^T[h*32+quad*8+j][l15]
  int sidxA = (2 * (quad & 1)) * 16 + l15;
  int sidxB = sidxA + 16;
  bool hiq = (quad & 2) != 0;
  F8 pf[2];
#pragma unroll
  for (int h = 0; h < 2; ++h) {
    u32 a0 = __shfl((int)pk[2 * h][0], sidxA), b0 = __shfl((int)pk[2 * h + 1][0], sidxA);
    u32 a1 = __shfl((int)pk[2 * h][1], sidxA), b1 = __shfl((int)pk[2 * h + 1][1], sidxA);
    u32 a2 = __shfl((int)pk[2 * h][0], sidxB), b2 = __shfl((int)pk[2 * h + 1][0], sidxB);
    u32 a3 = __shfl((int)pk[2 * h][1], sidxB), b3 = __shfl((int)pk[2 * h + 1][1], sidxB);
    pf[h].d[0] = hiq ? b0 : a0;
    pf[h].d[1] = hiq ? b1 : a1;
    pf[h].d[2] = hiq ? b2 : a2;
    pf[h].d[3] = hiq ? b3 : a3;
  }
  // O^T += V^T P^T
  int sl0 = ((0 + quad) ^ (l15 & 7)) * 8;
  int sl1 = ((4 + quad) ^ (l15 & 7)) * 8;
#pragma unroll
  for (int dt = 0; dt < 8; ++dt) {
    short8 va0 = *(const short8*)&Vsb[(dt * 16 + l15) * 64 + sl0];
    short8 va1 = *(const short8*)&Vsb[(dt * 16 + l15) * 64 + sl1];
    o[dt] = __builtin_amdgcn_mfma_f32_16x16x32_bf16(va0, pf[0].s, o[dt], 0, 0, 0);
    o[dt] = __builtin_amdgcn_mfma_f32_16x16x32_bf16(va1, pf[1].s, o[dt], 0, 0, 0);
  }
}

__global__ __launch_bounds__(256) void attn_kernel(const u16* __restrict__ qkv,
                                                   const u16* __restrict__ vt,
                                                   u16* __restrict__ CTX) {
  const int bx = blockIdx.x;         // 0..15; bx=0 heaviest, dispatched first
  const int bh = blockIdx.y;
  const int b = bh >> 5, h = bh & 31;
  const int g = h >> 2;
  const int bg = b * NKV + g;
  const int tid = threadIdx.x;
  const int w = tid >> 6, lane = tid & 63;
  const int l15 = lane & 15, quad = lane >> 4;
  const int lo = bx, hi = 31 - bx;
  const int niter = hi + 1;

  __shared__ u16 Ks[2 * 64 * 128];   // [kk][d] swizzled, dbuf
  __shared__ u16 Vs[2 * 128 * 64];   // [d][kk] swizzled, dbuf

  const u16* kbase = qkv + (size_t)(b * T_SEQ) * 6144 + 4096 + g * 128;
  const u16* vbase = vt + (size_t)(bg * 128) * T_SEQ;

  // Q B-operand fragments (lane holds q = l15's row)
  short8 aq[2][4];
  const int qg_lo = lo * 64 + w * 16 + l15;
  const int qg_hi = hi * 64 + w * 16 + l15;
  {
    const u16* qp0 = qkv + (size_t)(b * T_SEQ + qg_lo) * 6144 + h * 128;
    const u16* qp1 = qkv + (size_t)(b * T_SEQ + qg_hi) * 6144 + h * 128;
#pragma unroll
    for (int ks = 0; ks < 4; ++ks) {
      aq[0][ks] = *(const short8*)(qp0 + ks * 32 + quad * 8);
      aq[1][ks] = *(const short8*)(qp1 + ks * 32 + quad * 8);
    }
  }

  float m_s[2] = {-1e30f, -1e30f}, ell[2] = {0.f, 0.f};
  floatx4 o[2][8];
#pragma unroll
  for (int t = 0; t < 2; ++t)
#pragma unroll
    for (int dt = 0; dt < 8; ++dt)
#pragma unroll
      for (int r = 0; r < 4; ++r) o[t][dt][r] = 0.0f;

  // staging lane roles
  const int krloc = lane >> 4, kslot = lane & 15;
  const int vrloc = lane >> 3, vslot = lane & 7;

  // prologue: stage tile 0 into buf 0
  {
#pragma unroll
    for (int j = 0; j < 4; ++j) {
      int rk = w * 16 + j * 4 + krloc;
      int gck = (kslot & 8) | ((kslot & 7) ^ (rk & 7));
      GLD_LDS(kbase + (size_t)rk * 6144 + gck * 8, Ks + (w * 16 + j * 4) * 128);
      int rv = w * 32 + j * 8 + vrloc;
      int gcv = vslot ^ vrloc;
      GLD_LDS(vbase + (size_t)rv * 2048 + gcv * 8, Vs + (w * 32 + j * 8) * 64);
    }
  }

  for (int kt = 0; kt < niter; ++kt) {
    const int buf = kt & 1;
    const int k0 = kt * 64;
    __syncthreads();  // stage(kt) complete; all waves done reading buf^1 from kt-1

    if (kt + 1 < niter) {  // prefetch kt+1 into buf^1, overlapped with compute(kt)
      const int nb = buf ^ 1;
      const int k0n = k0 + 64;
#pragma unroll
      for (int j = 0; j < 4; ++j) {
        int rk = w * 16 + j * 4 + krloc;
        int gck = (kslot & 8) | ((kslot & 7) ^ (rk & 7));
        GLD_LDS(kbase + (size_t)(k0n + rk) * 6144 + gck * 8,
                Ks + nb * 8192 + (w * 16 + j * 4) * 128);
        int rv = w * 32 + j * 8 + vrloc;
        int gcv = vslot ^ vrloc;
        GLD_LDS(vbase + (size_t)rv * 2048 + k0n + gcv * 8,
                Vs + nb * 8192 + (w * 32 + j * 8) * 64);
      }
    }

    const u16* Ksb = Ks + buf * 8192;
    const u16* Vsb = Vs + buf * 8192;
    const bool lo_on = (kt <= lo);

    // S^T = K Q^T
    floatx4 s0[4], s1[4];
#pragma unroll
    for (int t4 = 0; t4 < 4; ++t4)
#pragma unroll
      for (int r = 0; r < 4; ++r) { s0[t4][r] = 0.f; s1[t4][r] = 0.f; }

    if (lo_on) {
#pragma unroll
      for (int ks = 0; ks < 4; ++ks) {
        int c = ks * 4 + quad;
        int sl = ((c & 8) | ((c & 7) ^ (l15 & 7))) * 8;
#pragma unroll
        for (int t4 = 0; t4 < 4; ++t4) {
          short8 bk = *(const short8*)&Ksb[(t4 * 16 + l15) * 128 + sl];
          s1[t4] = __builtin_amdgcn_mfma_f32_16x16x32_bf16(bk, aq[1][ks], s1[t4], 0, 0, 0);
          s0[t4] = __builtin_amdgcn_mfma_f32_16x16x32_bf16(bk, aq[0][ks], s0[t4], 0, 0, 0);
        }
      }
    } else {
#pragma unroll
      for (int ks = 0; ks < 4; ++ks) {
        int c = ks * 4 + quad;
        int sl = ((c & 8) | ((c & 7) ^ (l15 & 7))) * 8;
#pragma unroll
        for (int t4 = 0; t4 < 4; ++t4) {
          short8 bk = *(const short8*)&Ksb[(t4 * 16 + l15) * 128 + sl];
          s1[t4] = __builtin_amdgcn_mfma_f32_16x16x32_bf16(bk, aq[1][ks], s1[t4], 0, 0, 0);
        }
      }
    }

    softmax_pv(s1, m_s[1], ell[1], o[1], Vsb, qg_hi, k0, kt == hi, l15, quad);
    if (lo_on)
      softmax_pv(s0, m_s[0], ell[0], o[0], Vsb, qg_lo, k0, kt == lo, l15, quad);
  }

  // epilogue: O^T -> ctx (lane q = l15; 4 consecutive d per dt)
#pragma unroll
  for (int t = 0; t < 2; ++t) {
    float inv_l = 1.0f / ell[t];
    int qglob = (t ? qg_hi : qg_lo);
    u16* cp = CTX + (size_t)(b * T_SEQ + qglob) * 4096 + h * 128 + quad * 4;
#pragma unroll
    for (int dt = 0; dt < 8; ++dt) {
      ushort4 pkd;
      pkd.x = f2bf(o[t][dt][0] * inv_l);
      pkd.y = f2bf(o[t][dt][1] * inv_l);
      pkd.z = f2bf(o[t][dt][2] * inv_l);
      pkd.w = f2bf(o[t][dt][3] * inv_l);
      *(ushort4*)(cp + dt * 16) = pkd;
    }
  }
}

// ---------------- launcher ----------------
extern "C" void kernel_launch(void* const* d_in, const int* in_sizes, int n_in,
                              void* d_out, int out_size, void* d_ws, size_t ws_size,
                              hipStream_t stream) {
  const float* x  = (const float*)d_in[0];
  const float* Wq = (const float*)d_in[1];
  const float* Wk = (const float*)d_in[2];
  const float* Wv = (const float*)d_in[3];
  const float* Wo = (const float*)d_in[4];
  float* out = (float*)d_out;

  char* ws = (char*)d_ws;
  const size_t SZ_X    = (size_t)4096 * 4096 * 2;
  const size_t SZ_QKVW = (size_t)6144 * 4096 * 2;
  u16* xb    = (u16*)(ws);
  u16* wqkvT = (u16*)(ws + SZ_X);
  u16* woT   = (u16*)(ws + SZ_X + SZ_QKVW);
  u16* qkv   = (u16*)(ws + SZ_X + SZ_QKVW + SZ_X);
  u16* vt    = (u16*)(ws + SZ_X + SZ_QKVW + SZ_X + SZ_QKVW);
  u16* ctx   = xb;  // x dead after QKV GEMM

  cast_x_kernel<<<8192, 256, 0, stream>>>(x, xb, 2097152);
  transpose_cast_kernel<<<dim3(64, 64), 256, 0, stream>>>(Wq, wqkvT, 4096, 4096);
  transpose_cast_kernel<<<dim3(16, 64), 256, 0, stream>>>(Wk, wqkvT + (size_t)4096 * 4096, 4096, 1024);
  transpose_cast_kernel<<<dim3(16, 64), 256, 0, stream>>>(Wv, wqkvT + (size_t)5120 * 4096, 4096, 1024);
  transpose_cast_kernel<<<dim3(64, 64), 256, 0, stream>>>(Wo, woT, 4096, 4096);

  gemm_bt<u16><<<dim3(48, 32), 256, 0, stream>>>(xb, wqkvT, qkv, 4096, 6144, 4096, 6144);

  rope_kernel<<<40960, 256, 0, stream>>>(qkv);
  vtrans_kernel<<<dim3(32, 2, 16), 256, 0, stream>>>(qkv, vt);

  attn_kernel<<<dim3(16, 64), 256, 0, stream>>>(qkv, vt, ctx);

  gemm_bt<float><<<dim3(32, 32), 256, 0, stream>>>(ctx, woT, out, 4096, 4096, 4096, 4096);
}